// Round 8
// baseline (430.737 us; speedup 1.0000x reference)
//
#include <hip/hip_runtime.h>

#define N_IN 256
#define N_OUT 64
#define NEG_SLOPE 0.01f

typedef __attribute__((ext_vector_type(8))) short short8v;   // 8 bf16
typedef __attribute__((ext_vector_type(4))) float float4v;   // MFMA acc

__device__ inline short f32_to_bf16_rtne(float f) {
    unsigned u = __float_as_uint(f);
    unsigned r = (u + 0x7FFFu + ((u >> 16) & 1u)) >> 16;
    return (short)r;
}

// ---------------------------------------------------------------------------
// Kernel 1: z = h @ W.T via bf16 MFMA, fused logits s_node/d_node.
// ---------------------------------------------------------------------------
constexpr int GM = 64;
constexpr int KP = 264;   // padded K (bf16 units); 528 B row stride, 16B-aligned

__global__ __launch_bounds__(256) void gemm_zsd_mfma(
    const float* __restrict__ h, const float* __restrict__ W,
    const float* __restrict__ A,
    float* __restrict__ z, float* __restrict__ s_node, float* __restrict__ d_node,
    int n_nodes)
{
    __shared__ short hA[GM * KP];
    __shared__ short wB[N_OUT * KP];
    const int t = threadIdx.x;
    const int row0 = blockIdx.x * GM;

    // ---- stage h tile and W, f32 -> bf16(RTNE), 8 cols (16B) per write ----
    for (int j = 0; j < 8; ++j) {
        const int f  = j * 256 + t;      // 8-col group index
        const int r  = f >> 5;           // row 0..63
        const int c8 = f & 31;           // 8-col group 0..31

        int grow = row0 + r;
        if (grow >= n_nodes) grow = n_nodes - 1;   // clamp (tail block)
        const float4* ph = reinterpret_cast<const float4*>(h + (size_t)grow * N_IN + c8 * 8);
        float4 h0 = ph[0], h1 = ph[1];
        short8v pkh;
        pkh[0] = f32_to_bf16_rtne(h0.x); pkh[1] = f32_to_bf16_rtne(h0.y);
        pkh[2] = f32_to_bf16_rtne(h0.z); pkh[3] = f32_to_bf16_rtne(h0.w);
        pkh[4] = f32_to_bf16_rtne(h1.x); pkh[5] = f32_to_bf16_rtne(h1.y);
        pkh[6] = f32_to_bf16_rtne(h1.z); pkh[7] = f32_to_bf16_rtne(h1.w);
        *reinterpret_cast<short8v*>(&hA[r * KP + c8 * 8]) = pkh;

        const float4* pw = reinterpret_cast<const float4*>(W + (size_t)r * N_IN + c8 * 8);
        float4 w0 = pw[0], w1 = pw[1];
        short8v pkw;
        pkw[0] = f32_to_bf16_rtne(w0.x); pkw[1] = f32_to_bf16_rtne(w0.y);
        pkw[2] = f32_to_bf16_rtne(w0.z); pkw[3] = f32_to_bf16_rtne(w0.w);
        pkw[4] = f32_to_bf16_rtne(w1.x); pkw[5] = f32_to_bf16_rtne(w1.y);
        pkw[6] = f32_to_bf16_rtne(w1.z); pkw[7] = f32_to_bf16_rtne(w1.w);
        *reinterpret_cast<short8v*>(&wB[r * KP + c8 * 8]) = pkw;
    }
    __syncthreads();

    const int w  = t >> 6;    // wave id
    const int l  = t & 63;
    const int lr = l & 15;    // A row / B col / C col within 16
    const int lk = l >> 4;    // k-group (0..3)

    float4v acc[4] = {{0.f,0.f,0.f,0.f},{0.f,0.f,0.f,0.f},
                      {0.f,0.f,0.f,0.f},{0.f,0.f,0.f,0.f}};

    for (int kk = 0; kk < 8; ++kk) {                 // K-steps of 32
        const int kbase = kk * 32 + lk * 8;
        const short8v a = *reinterpret_cast<const short8v*>(&hA[(w * 16 + lr) * KP + kbase]);
#pragma unroll
        for (int n = 0; n < 4; ++n) {
            const short8v b = *reinterpret_cast<const short8v*>(&wB[(n * 16 + lr) * KP + kbase]);
            acc[n] = __builtin_amdgcn_mfma_f32_16x16x32_bf16(a, b, acc[n], 0, 0, 0);
        }
    }

    // ---- epilogue: write z (f32), fused s/d logits ----
    float as[4], ad[4];
#pragma unroll
    for (int n = 0; n < 4; ++n) {
        as[n] = A[n * 16 + lr];
        ad[n] = A[N_OUT + n * 16 + lr];
    }

    float sv[4] = {0.f,0.f,0.f,0.f}, dv[4] = {0.f,0.f,0.f,0.f};
#pragma unroll
    for (int n = 0; n < 4; ++n) {
#pragma unroll
        for (int r = 0; r < 4; ++r) {
            const float v = acc[n][r];
            const int grow = row0 + w * 16 + lk * 4 + r;
            if (grow < n_nodes) z[(size_t)grow * N_OUT + n * 16 + lr] = v;
            sv[r] = fmaf(v, as[n], sv[r]);
            dv[r] = fmaf(v, ad[n], dv[r]);
        }
    }
    // reduce over the 16 lanes (lr) of each lk-group
#pragma unroll
    for (int off = 1; off < 16; off <<= 1) {
#pragma unroll
        for (int r = 0; r < 4; ++r) {
            sv[r] += __shfl_xor(sv[r], off);
            dv[r] += __shfl_xor(dv[r], off);
        }
    }
    if (lr == 0) {
#pragma unroll
        for (int r = 0; r < 4; ++r) {
            const int grow = row0 + w * 16 + lk * 4 + r;
            if (grow < n_nodes) { s_node[grow] = sv[r]; d_node[grow] = dv[r]; }
        }
    }
}

// ---------------------------------------------------------------------------
// Kernel 2: histogram of dst  (counts must be pre-zeroed)
// ---------------------------------------------------------------------------
__global__ __launch_bounds__(256) void count_dst(
    const int* __restrict__ dst, int* __restrict__ counts, int n_edges)
{
    int i = blockIdx.x * blockDim.x + threadIdx.x;
    const int stride = gridDim.x * blockDim.x;
    for (; i < n_edges; i += stride)
        atomicAdd(&counts[dst[i]], 1);
}

// ---------------------------------------------------------------------------
// Kernel 3a: per-block exclusive scan (in-place) + block totals
// ---------------------------------------------------------------------------
__global__ __launch_bounds__(1024) void scan_block(
    int* __restrict__ data, int* __restrict__ partials, int n)
{
    __shared__ int tmp[1024];
    const int gid = blockIdx.x * 1024 + threadIdx.x;
    const int v = (gid < n) ? data[gid] : 0;
    tmp[threadIdx.x] = v;
    __syncthreads();
    for (int off = 1; off < 1024; off <<= 1) {
        int t = (threadIdx.x >= off) ? tmp[threadIdx.x - off] : 0;
        __syncthreads();
        tmp[threadIdx.x] += t;
        __syncthreads();
    }
    const int incl = tmp[threadIdx.x];
    if (gid < n) data[gid] = incl - v;               // exclusive within block
    if (threadIdx.x == 1023) partials[blockIdx.x] = incl;
}

// Kernel 3b: exclusive scan of block totals (single block, nb <= 128)
__global__ __launch_bounds__(128) void scan_partials(int* __restrict__ partials, int nb)
{
    __shared__ int tmp[128];
    const int v = (threadIdx.x < nb) ? partials[threadIdx.x] : 0;
    tmp[threadIdx.x] = v;
    __syncthreads();
    for (int off = 1; off < 128; off <<= 1) {
        int t = (threadIdx.x >= off) ? tmp[threadIdx.x - off] : 0;
        __syncthreads();
        tmp[threadIdx.x] += t;
        __syncthreads();
    }
    if (threadIdx.x < nb) partials[threadIdx.x] = tmp[threadIdx.x] - v;
}

// Kernel 3c: add scanned block bases -> full exclusive scan (segment starts)
__global__ __launch_bounds__(256) void scan_add_base(
    int* __restrict__ data, const int* __restrict__ partials, int n)
{
    const int gid = blockIdx.x * blockDim.x + threadIdx.x;
    if (gid < n) data[gid] += partials[gid >> 10];
}

// ---------------------------------------------------------------------------
// Kernel 4: p = exp(leakyrelu(s[src]+d[dst])); scatter {src,p} to dst-sorted
// order. Blocked-by-4 per thread: int4 loads, 4 independent gather/atomic/
// write chains in flight (was 1 -> latency-bound at VALUBusy 1%).
// ---------------------------------------------------------------------------
__global__ __launch_bounds__(256) void edge_scatter(
    const int* __restrict__ src, const int* __restrict__ dst,
    const float* __restrict__ s_node, const float* __restrict__ d_node,
    int* __restrict__ cursor, int2* __restrict__ edges, int n_edges)
{
    const int tid = blockIdx.x * blockDim.x + threadIdx.x;
    const int base = tid * 4;
    if (base >= n_edges) return;
    if (base + 4 <= n_edges) {
        const int4 s4 = reinterpret_cast<const int4*>(src)[tid];
        const int4 d4 = reinterpret_cast<const int4*>(dst)[tid];
        float e0 = s_node[s4.x] + d_node[d4.x];
        float e1 = s_node[s4.y] + d_node[d4.y];
        float e2 = s_node[s4.z] + d_node[d4.z];
        float e3 = s_node[s4.w] + d_node[d4.w];
        e0 = (e0 >= 0.f) ? e0 : NEG_SLOPE * e0;
        e1 = (e1 >= 0.f) ? e1 : NEG_SLOPE * e1;
        e2 = (e2 >= 0.f) ? e2 : NEG_SLOPE * e2;
        e3 = (e3 >= 0.f) ? e3 : NEG_SLOPE * e3;
        const float p0 = __expf(e0), p1 = __expf(e1);
        const float p2 = __expf(e2), p3 = __expf(e3);
        const int pos0 = atomicAdd(&cursor[d4.x], 1);
        const int pos1 = atomicAdd(&cursor[d4.y], 1);
        const int pos2 = atomicAdd(&cursor[d4.z], 1);
        const int pos3 = atomicAdd(&cursor[d4.w], 1);
        edges[pos0] = make_int2(s4.x, __float_as_int(p0));
        edges[pos1] = make_int2(s4.y, __float_as_int(p1));
        edges[pos2] = make_int2(s4.z, __float_as_int(p2));
        edges[pos3] = make_int2(s4.w, __float_as_int(p3));
    } else {
        for (int i = base; i < n_edges; ++i) {
            const int s = src[i], d = dst[i];
            float e = s_node[s] + d_node[d];
            e = (e >= 0.f) ? e : NEG_SLOPE * e;
            const float pe = __expf(e);
            const int pos = atomicAdd(&cursor[d], 1);
            edges[pos] = make_int2(s, __float_as_int(pe));
        }
    }
}

// ---------------------------------------------------------------------------
// Kernel 5: one wave per dst node; 16 lanes per edge, 4 edge slots; unroll-4
// main loop keeps 16 z-rows in flight per wave.
// ---------------------------------------------------------------------------
__global__ __launch_bounds__(256) void gather_accum(
    const int2* __restrict__ edges, const int* __restrict__ segend,
    const float* __restrict__ z, float* __restrict__ out, int n_nodes)
{
    const int wave = (blockIdx.x * 256 + threadIdx.x) >> 6;
    const int lane = threadIdx.x & 63;
    if (wave >= n_nodes) return;
    const int sub = lane >> 4;   // edge slot 0..3
    const int l16 = lane & 15;   // float4 index within row
    const int end   = segend[wave];
    const int start = (wave == 0) ? 0 : segend[wave - 1];

    float ax = 0.f, ay = 0.f, az = 0.f, aw = 0.f, denom = 0.f;
    int i = start + sub;
    for (; i + 12 < end; i += 16) {
        const int2 e0 = edges[i];
        const int2 e1 = edges[i + 4];
        const int2 e2 = edges[i + 8];
        const int2 e3 = edges[i + 12];
        const float4 z0 = reinterpret_cast<const float4*>(z + (size_t)e0.x * N_OUT)[l16];
        const float4 z1 = reinterpret_cast<const float4*>(z + (size_t)e1.x * N_OUT)[l16];
        const float4 z2 = reinterpret_cast<const float4*>(z + (size_t)e2.x * N_OUT)[l16];
        const float4 z3 = reinterpret_cast<const float4*>(z + (size_t)e3.x * N_OUT)[l16];
        const float p0 = __int_as_float(e0.y);
        const float p1 = __int_as_float(e1.y);
        const float p2 = __int_as_float(e2.y);
        const float p3 = __int_as_float(e3.y);
        denom += (p0 + p1) + (p2 + p3);
        ax = fmaf(p0, z0.x, ax); ay = fmaf(p0, z0.y, ay);
        az = fmaf(p0, z0.z, az); aw = fmaf(p0, z0.w, aw);
        ax = fmaf(p1, z1.x, ax); ay = fmaf(p1, z1.y, ay);
        az = fmaf(p1, z1.z, az); aw = fmaf(p1, z1.w, aw);
        ax = fmaf(p2, z2.x, ax); ay = fmaf(p2, z2.y, ay);
        az = fmaf(p2, z2.z, az); aw = fmaf(p2, z2.w, aw);
        ax = fmaf(p3, z3.x, ax); ay = fmaf(p3, z3.y, ay);
        az = fmaf(p3, z3.z, az); aw = fmaf(p3, z3.w, aw);
    }
    for (; i < end; i += 4) {
        const int2 e0 = edges[i];
        const float4 z0 = reinterpret_cast<const float4*>(z + (size_t)e0.x * N_OUT)[l16];
        const float p0 = __int_as_float(e0.y);
        denom += p0;
        ax = fmaf(p0, z0.x, ax); ay = fmaf(p0, z0.y, ay);
        az = fmaf(p0, z0.z, az); aw = fmaf(p0, z0.w, aw);
    }
    // reduce across the 4 edge slots (lanes l16, l16+16, l16+32, l16+48)
#pragma unroll
    for (int off = 16; off < 64; off <<= 1) {
        ax += __shfl_xor(ax, off);
        ay += __shfl_xor(ay, off);
        az += __shfl_xor(az, off);
        aw += __shfl_xor(aw, off);
        denom += __shfl_xor(denom, off);
    }
    if (sub == 0) {
        const float inv = (end > start) ? 1.f / denom : 0.f;
        float4 r;
        r.x = ax * inv; r.y = ay * inv; r.z = az * inv; r.w = aw * inv;
        reinterpret_cast<float4*>(out + (size_t)wave * N_OUT)[l16] = r;
    }
}

// ---------------------------------------------------------------------------
extern "C" void kernel_launch(void* const* d_in, const int* in_sizes, int n_in,
                              void* d_out, int out_size, void* d_ws, size_t ws_size,
                              hipStream_t stream) {
    const float* h = (const float*)d_in[0];
    const float* W = (const float*)d_in[1];
    const float* A = (const float*)d_in[2];
    const int* src = (const int*)d_in[3];
    const int* dst = (const int*)d_in[4];
    float* out = (float*)d_out;

    const int n_nodes = in_sizes[0] / N_IN;
    const int n_edges = in_sizes[3];

    // workspace layout (all offsets keep 8B alignment for the int2 array)
    char* ws = (char*)d_ws;
    float* z      = (float*)ws;                    ws += (size_t)n_nodes * N_OUT * 4;
    float* s_node = (float*)ws;                    ws += (size_t)n_nodes * 4;
    float* d_node = (float*)ws;                    ws += (size_t)n_nodes * 4;
    int*   counts = (int*)ws;                      ws += (size_t)n_nodes * 4;   // -> offsets -> segends
    int*   parts  = (int*)ws;                      ws += 512;
    int2*  edges  = (int2*)ws;

    const int nb_scan = (n_nodes + 1023) / 1024;   // 98 <= 128

    // zero the histogram only (kernel 5 writes every out element)
    hipMemsetAsync(counts, 0, (size_t)n_nodes * sizeof(int), stream);

    // 1) GEMM + logits (bf16 MFMA)
    gemm_zsd_mfma<<<(n_nodes + GM - 1) / GM, 256, 0, stream>>>(h, W, A, z, s_node, d_node, n_nodes);

    // 2) dst histogram
    count_dst<<<1024, 256, 0, stream>>>(dst, counts, n_edges);

    // 3) exclusive scan -> segment starts
    scan_block<<<nb_scan, 1024, 0, stream>>>(counts, parts, n_nodes);
    scan_partials<<<1, 128, 0, stream>>>(parts, nb_scan);
    scan_add_base<<<(n_nodes + 255) / 256, 256, 0, stream>>>(counts, parts, n_nodes);

    // 4) compute p and scatter into dst-sorted order (counts -> segment ends)
    const int nthr4 = (n_edges + 3) / 4;
    edge_scatter<<<(nthr4 + 255) / 256, 256, 0, stream>>>(src, dst, s_node, d_node, counts, edges, n_edges);

    // 5) per-dst register accumulate, single write of out
    gather_accum<<<(n_nodes * 64 + 255) / 256, 256, 0, stream>>>(edges, counts, z, out, n_nodes);
}

// Round 11
// 382.691 us; speedup vs baseline: 1.1255x; 1.1255x over previous
//
#include <hip/hip_runtime.h>

#define N_IN 256
#define N_OUT 64
#define NEG_SLOPE 0.01f

typedef __attribute__((ext_vector_type(8))) short short8v;   // 8 bf16
typedef __attribute__((ext_vector_type(4))) float float4v;   // MFMA acc

__device__ inline short f32_to_bf16_rtne(float f) {
    unsigned u = __float_as_uint(f);
    unsigned r = (u + 0x7FFFu + ((u >> 16) & 1u)) >> 16;
    return (short)r;
}

// ---------------------------------------------------------------------------
// Kernel 1: z = h @ W.T via bf16 MFMA, fused logits s_node/d_node.
// ---------------------------------------------------------------------------
constexpr int GM = 64;
constexpr int KP = 264;   // padded K (bf16 units); 528 B row stride, 16B-aligned

__global__ __launch_bounds__(256) void gemm_zsd_mfma(
    const float* __restrict__ h, const float* __restrict__ W,
    const float* __restrict__ A,
    float* __restrict__ z, float* __restrict__ s_node, float* __restrict__ d_node,
    int n_nodes)
{
    __shared__ short hA[GM * KP];
    __shared__ short wB[N_OUT * KP];
    const int t = threadIdx.x;
    const int row0 = blockIdx.x * GM;

    // ---- stage h tile and W, f32 -> bf16(RTNE), 8 cols (16B) per write ----
    for (int j = 0; j < 8; ++j) {
        const int f  = j * 256 + t;      // 8-col group index
        const int r  = f >> 5;           // row 0..63
        const int c8 = f & 31;           // 8-col group 0..31

        int grow = row0 + r;
        if (grow >= n_nodes) grow = n_nodes - 1;   // clamp (tail block)
        const float4* ph = reinterpret_cast<const float4*>(h + (size_t)grow * N_IN + c8 * 8);
        float4 h0 = ph[0], h1 = ph[1];
        short8v pkh;
        pkh[0] = f32_to_bf16_rtne(h0.x); pkh[1] = f32_to_bf16_rtne(h0.y);
        pkh[2] = f32_to_bf16_rtne(h0.z); pkh[3] = f32_to_bf16_rtne(h0.w);
        pkh[4] = f32_to_bf16_rtne(h1.x); pkh[5] = f32_to_bf16_rtne(h1.y);
        pkh[6] = f32_to_bf16_rtne(h1.z); pkh[7] = f32_to_bf16_rtne(h1.w);
        *reinterpret_cast<short8v*>(&hA[r * KP + c8 * 8]) = pkh;

        const float4* pw = reinterpret_cast<const float4*>(W + (size_t)r * N_IN + c8 * 8);
        float4 w0 = pw[0], w1 = pw[1];
        short8v pkw;
        pkw[0] = f32_to_bf16_rtne(w0.x); pkw[1] = f32_to_bf16_rtne(w0.y);
        pkw[2] = f32_to_bf16_rtne(w0.z); pkw[3] = f32_to_bf16_rtne(w0.w);
        pkw[4] = f32_to_bf16_rtne(w1.x); pkw[5] = f32_to_bf16_rtne(w1.y);
        pkw[6] = f32_to_bf16_rtne(w1.z); pkw[7] = f32_to_bf16_rtne(w1.w);
        *reinterpret_cast<short8v*>(&wB[r * KP + c8 * 8]) = pkw;
    }
    __syncthreads();

    const int w  = t >> 6;    // wave id
    const int l  = t & 63;
    const int lr = l & 15;    // A row / B col / C col within 16
    const int lk = l >> 4;    // k-group (0..3)

    float4v acc[4] = {{0.f,0.f,0.f,0.f},{0.f,0.f,0.f,0.f},
                      {0.f,0.f,0.f,0.f},{0.f,0.f,0.f,0.f}};

    for (int kk = 0; kk < 8; ++kk) {                 // K-steps of 32
        const int kbase = kk * 32 + lk * 8;
        const short8v a = *reinterpret_cast<const short8v*>(&hA[(w * 16 + lr) * KP + kbase]);
#pragma unroll
        for (int n = 0; n < 4; ++n) {
            const short8v b = *reinterpret_cast<const short8v*>(&wB[(n * 16 + lr) * KP + kbase]);
            acc[n] = __builtin_amdgcn_mfma_f32_16x16x32_bf16(a, b, acc[n], 0, 0, 0);
        }
    }

    // ---- epilogue: write z (f32), fused s/d logits ----
    float as[4], ad[4];
#pragma unroll
    for (int n = 0; n < 4; ++n) {
        as[n] = A[n * 16 + lr];
        ad[n] = A[N_OUT + n * 16 + lr];
    }

    float sv[4] = {0.f,0.f,0.f,0.f}, dv[4] = {0.f,0.f,0.f,0.f};
#pragma unroll
    for (int n = 0; n < 4; ++n) {
#pragma unroll
        for (int r = 0; r < 4; ++r) {
            const float v = acc[n][r];
            const int grow = row0 + w * 16 + lk * 4 + r;
            if (grow < n_nodes) z[(size_t)grow * N_OUT + n * 16 + lr] = v;
            sv[r] = fmaf(v, as[n], sv[r]);
            dv[r] = fmaf(v, ad[n], dv[r]);
        }
    }
    // reduce over the 16 lanes (lr) of each lk-group
#pragma unroll
    for (int off = 1; off < 16; off <<= 1) {
#pragma unroll
        for (int r = 0; r < 4; ++r) {
            sv[r] += __shfl_xor(sv[r], off);
            dv[r] += __shfl_xor(dv[r], off);
        }
    }
    if (lr == 0) {
#pragma unroll
        for (int r = 0; r < 4; ++r) {
            const int grow = row0 + w * 16 + lk * 4 + r;
            if (grow < n_nodes) { s_node[grow] = sv[r]; d_node[grow] = dv[r]; }
        }
    }
}

// ---------------------------------------------------------------------------
// Kernel 2: histogram of dst  (counts must be pre-zeroed)
// ---------------------------------------------------------------------------
__global__ __launch_bounds__(256) void count_dst(
    const int* __restrict__ dst, int* __restrict__ counts, int n_edges)
{
    int i = blockIdx.x * blockDim.x + threadIdx.x;
    const int stride = gridDim.x * blockDim.x;
    for (; i < n_edges; i += stride)
        atomicAdd(&counts[dst[i]], 1);
}

// ---------------------------------------------------------------------------
// Kernel 3a: per-block exclusive scan (in-place) + block totals
// ---------------------------------------------------------------------------
__global__ __launch_bounds__(1024) void scan_block(
    int* __restrict__ data, int* __restrict__ partials, int n)
{
    __shared__ int tmp[1024];
    const int gid = blockIdx.x * 1024 + threadIdx.x;
    const int v = (gid < n) ? data[gid] : 0;
    tmp[threadIdx.x] = v;
    __syncthreads();
    for (int off = 1; off < 1024; off <<= 1) {
        int t = (threadIdx.x >= off) ? tmp[threadIdx.x - off] : 0;
        __syncthreads();
        tmp[threadIdx.x] += t;
        __syncthreads();
    }
    const int incl = tmp[threadIdx.x];
    if (gid < n) data[gid] = incl - v;               // exclusive within block
    if (threadIdx.x == 1023) partials[blockIdx.x] = incl;
}

// Kernel 3b: exclusive scan of block totals (single block, nb <= 128)
__global__ __launch_bounds__(128) void scan_partials(int* __restrict__ partials, int nb)
{
    __shared__ int tmp[128];
    const int v = (threadIdx.x < nb) ? partials[threadIdx.x] : 0;
    tmp[threadIdx.x] = v;
    __syncthreads();
    for (int off = 1; off < 128; off <<= 1) {
        int t = (threadIdx.x >= off) ? tmp[threadIdx.x - off] : 0;
        __syncthreads();
        tmp[threadIdx.x] += t;
        __syncthreads();
    }
    if (threadIdx.x < nb) partials[threadIdx.x] = tmp[threadIdx.x] - v;
}

// Kernel 3c: add scanned block bases -> full exclusive scan (segment starts)
__global__ __launch_bounds__(256) void scan_add_base(
    int* __restrict__ data, const int* __restrict__ partials, int n)
{
    const int gid = blockIdx.x * blockDim.x + threadIdx.x;
    if (gid < n) data[gid] += partials[gid >> 10];
}

// ---------------------------------------------------------------------------
// Kernel 4: p = exp(leakyrelu(s[src]+d[dst])); scatter {src,p} to dst-sorted
// order. XCD-ownership: block bid handles only dsts in region bid&7; under
// round-robin block->XCD dispatch all writes to an edges[] line (and all
// cursor atomics for a dst) come from one XCD's L2 -> line-level write
// amplification (was 64B/edge) collapses. Correct for ANY block->XCD
// mapping: each edge is processed by exactly one cohort.
// ---------------------------------------------------------------------------
__global__ __launch_bounds__(256) void edge_scatter(
    const int* __restrict__ src, const int* __restrict__ dst,
    const float* __restrict__ s_node, const float* __restrict__ d_node,
    int* __restrict__ cursor, int2* __restrict__ edges, int n_edges, int div8)
{
    const int my  = blockIdx.x & 7;                  // presumed XCD id
    const int cb  = blockIdx.x >> 3;                 // block index within cohort
    const int cbl = gridDim.x >> 3;                  // blocks per cohort
    int i = cb * blockDim.x + threadIdx.x;
    const int stride = cbl * blockDim.x;
    for (; i < n_edges; i += stride) {
        const int d = dst[i];
        if (d / div8 != my) continue;
        const int s = src[i];
        float e = s_node[s] + d_node[d];
        e = (e >= 0.f) ? e : NEG_SLOPE * e;
        const float pe = __expf(e);
        const int pos = atomicAdd(&cursor[d], 1);
        edges[pos] = make_int2(s, __float_as_int(pe));
    }
}

// ---------------------------------------------------------------------------
// Kernel 5: one wave per dst node; 16 lanes per edge, 4 edge slots; unroll-4
// main loop keeps 16 z-rows in flight per wave.
// ---------------------------------------------------------------------------
__global__ __launch_bounds__(256) void gather_accum(
    const int2* __restrict__ edges, const int* __restrict__ segend,
    const float* __restrict__ z, float* __restrict__ out, int n_nodes)
{
    const int wave = (blockIdx.x * 256 + threadIdx.x) >> 6;
    const int lane = threadIdx.x & 63;
    if (wave >= n_nodes) return;
    const int sub = lane >> 4;   // edge slot 0..3
    const int l16 = lane & 15;   // float4 index within row
    const int end   = segend[wave];
    const int start = (wave == 0) ? 0 : segend[wave - 1];

    float ax = 0.f, ay = 0.f, az = 0.f, aw = 0.f, denom = 0.f;
    int i = start + sub;
    for (; i + 12 < end; i += 16) {
        const int2 e0 = edges[i];
        const int2 e1 = edges[i + 4];
        const int2 e2 = edges[i + 8];
        const int2 e3 = edges[i + 12];
        const float4 z0 = reinterpret_cast<const float4*>(z + (size_t)e0.x * N_OUT)[l16];
        const float4 z1 = reinterpret_cast<const float4*>(z + (size_t)e1.x * N_OUT)[l16];
        const float4 z2 = reinterpret_cast<const float4*>(z + (size_t)e2.x * N_OUT)[l16];
        const float4 z3 = reinterpret_cast<const float4*>(z + (size_t)e3.x * N_OUT)[l16];
        const float p0 = __int_as_float(e0.y);
        const float p1 = __int_as_float(e1.y);
        const float p2 = __int_as_float(e2.y);
        const float p3 = __int_as_float(e3.y);
        denom += (p0 + p1) + (p2 + p3);
        ax = fmaf(p0, z0.x, ax); ay = fmaf(p0, z0.y, ay);
        az = fmaf(p0, z0.z, az); aw = fmaf(p0, z0.w, aw);
        ax = fmaf(p1, z1.x, ax); ay = fmaf(p1, z1.y, ay);
        az = fmaf(p1, z1.z, az); aw = fmaf(p1, z1.w, aw);
        ax = fmaf(p2, z2.x, ax); ay = fmaf(p2, z2.y, ay);
        az = fmaf(p2, z2.z, az); aw = fmaf(p2, z2.w, aw);
        ax = fmaf(p3, z3.x, ax); ay = fmaf(p3, z3.y, ay);
        az = fmaf(p3, z3.z, az); aw = fmaf(p3, z3.w, aw);
    }
    for (; i < end; i += 4) {
        const int2 e0 = edges[i];
        const float4 z0 = reinterpret_cast<const float4*>(z + (size_t)e0.x * N_OUT)[l16];
        const float p0 = __int_as_float(e0.y);
        denom += p0;
        ax = fmaf(p0, z0.x, ax); ay = fmaf(p0, z0.y, ay);
        az = fmaf(p0, z0.z, az); aw = fmaf(p0, z0.w, aw);
    }
    // reduce across the 4 edge slots (lanes l16, l16+16, l16+32, l16+48)
#pragma unroll
    for (int off = 16; off < 64; off <<= 1) {
        ax += __shfl_xor(ax, off);
        ay += __shfl_xor(ay, off);
        az += __shfl_xor(az, off);
        aw += __shfl_xor(aw, off);
        denom += __shfl_xor(denom, off);
    }
    if (sub == 0) {
        const float inv = (end > start) ? 1.f / denom : 0.f;
        float4 r;
        r.x = ax * inv; r.y = ay * inv; r.z = az * inv; r.w = aw * inv;
        reinterpret_cast<float4*>(out + (size_t)wave * N_OUT)[l16] = r;
    }
}

// ---------------------------------------------------------------------------
extern "C" void kernel_launch(void* const* d_in, const int* in_sizes, int n_in,
                              void* d_out, int out_size, void* d_ws, size_t ws_size,
                              hipStream_t stream) {
    const float* h = (const float*)d_in[0];
    const float* W = (const float*)d_in[1];
    const float* A = (const float*)d_in[2];
    const int* src = (const int*)d_in[3];
    const int* dst = (const int*)d_in[4];
    float* out = (float*)d_out;

    const int n_nodes = in_sizes[0] / N_IN;
    const int n_edges = in_sizes[3];

    // workspace layout (all offsets keep 8B alignment for the int2 array)
    char* ws = (char*)d_ws;
    float* z      = (float*)ws;                    ws += (size_t)n_nodes * N_OUT * 4;
    float* s_node = (float*)ws;                    ws += (size_t)n_nodes * 4;
    float* d_node = (float*)ws;                    ws += (size_t)n_nodes * 4;
    int*   counts = (int*)ws;                      ws += (size_t)n_nodes * 4;   // -> offsets -> segends
    int*   parts  = (int*)ws;                      ws += 512;
    int2*  edges  = (int2*)ws;

    const int nb_scan = (n_nodes + 1023) / 1024;   // 98 <= 128

    // zero the histogram only (kernel 5 writes every out element)
    hipMemsetAsync(counts, 0, (size_t)n_nodes * sizeof(int), stream);

    // 1) GEMM + logits (bf16 MFMA)
    gemm_zsd_mfma<<<(n_nodes + GM - 1) / GM, 256, 0, stream>>>(h, W, A, z, s_node, d_node, n_nodes);

    // 2) dst histogram
    count_dst<<<1024, 256, 0, stream>>>(dst, counts, n_edges);

    // 3) exclusive scan -> segment starts
    scan_block<<<nb_scan, 1024, 0, stream>>>(counts, parts, n_nodes);
    scan_partials<<<1, 128, 0, stream>>>(parts, nb_scan);
    scan_add_base<<<(n_nodes + 255) / 256, 256, 0, stream>>>(counts, parts, n_nodes);

    // 4) compute p and scatter into dst-sorted order (counts -> segment ends)
    const int div8 = (n_nodes + 7) / 8;
    edge_scatter<<<2048, 256, 0, stream>>>(src, dst, s_node, d_node, counts, edges, n_edges, div8);

    // 5) per-dst register accumulate, single write of out
    gather_accum<<<(n_nodes * 64 + 255) / 256, 256, 0, stream>>>(edges, counts, z, out, n_nodes);
}